// Round 18
// baseline (78.441 us; speedup 1.0000x reference)
//
#include <hip/hip_runtime.h>
#include <stdint.h>

// SpatialShiftConvBlock (B=8,T=64,N=21,C=128,F=256):
//   xs[b,t,n,c] = x[b,t,(n - c%21) mod 21, c]       (per-channel circular roll)
//   y  = xs @ W (+ b == 0, and bias cancels in BN anyway)
//   y  = (y - mean)*rsqrt(var + 1e-3)*gamma + beta  (BN training stats over B,T,N)
//   out = relu(y)  (float32 output)
//
// R46 = R45 (77.3us, best) + slab-pairing in k_conv:
//  grid 256 (= CU count, single round), each block does 2 adjacent bt-slabs:
//   - B-frags (16 dwordx4 -> 64 VGPR) loaded ONCE, used for both slabs.
//   - Pair's x is contiguous (42 rows): one staging loop, 1344 dwordx4 into
//     2 LDS A-buffers (17.4KB); all ~21 VMEM issues/thread hoisted before use.
//   - acc reused between slabs (s/q carried in 8 regs across both) -> ~140
//     VGPR, no spill; single epilogue: atomics halve (256 blk x 512, 8/addr).
//  k_prep / k_bnapply identical to R45.
// Frag maps (HW-verified m89): A: row=l&15,k=(l>>4)*8+j; B: col=l&15 same k;
// C/D: col=l&15,row=(l>>4)*4+reg.
// ws floats: [0:16384] 32x{256 sums,256 sumsqs}; [16384:32768] bf16 W frags;
// [32768:...] bf16 pre-norm y [10752][256] (5.5MB).
// fillBufferAligned (~41us harness ws re-poison) is an unconditional tax.

#define NPOS 21
#define CIN  128
#define FOUT 256
#define BT   512            // B*T
#define M_TOTAL 10752       // BT*NPOS
#define BN_EPS 1e-3f
#define AROW 136            // A LDS row stride in bf16 (272B: 16B-aligned)
#define PARTS 32
#define WSFRAG 16384        // float offset of W frags
#define WSY    32768        // float offset of bf16 pre-norm y

typedef short v8s __attribute__((ext_vector_type(8)));   // 8 bf16 (4 VGPR)
typedef float v4f __attribute__((ext_vector_type(4)));   // 4 f32 acc

__device__ __forceinline__ uint16_t f2bf_rne(float f) {
    uint32_t u = __builtin_bit_cast(uint32_t, f);
    u += 0x7FFFu + ((u >> 16) & 1u);                     // round-nearest-even
    return (uint16_t)(u >> 16);
}
__device__ __forceinline__ float bf2f_lo(uint32_t d) {
    return __builtin_bit_cast(float, d << 16);
}
__device__ __forceinline__ float bf2f_hi(uint32_t d) {
    return __builtin_bit_cast(float, d & 0xFFFF0000u);
}

// 16 blocks x 256: zero the 32 partial arrays (64KB); convert W -> bf16 frags.
__global__ __launch_bounds__(256) void k_prep(const float* __restrict__ W,
                                              float* __restrict__ ws)
{
    const int t = threadIdx.x;
    const int b = blockIdx.x;
    ((float4*)ws)[b * 256 + t] = make_float4(0.f, 0.f, 0.f, 0.f);  // [0:16384]

    const int q  = b * 256 + t;                          // frag id 0..4095
    const int l  = q & 63;
    const int ks = (q >> 6) & 3;
    const int nt = q >> 8;                               // n-tile 0..15
    const int kb = ks * 32 + (l >> 4) * 8;
    const int col = nt * 16 + (l & 15);
    uint32_t d[4];
    #pragma unroll
    for (int p = 0; p < 4; p++) {
        uint32_t lo = f2bf_rne(W[(size_t)(kb + 2 * p    ) * FOUT + col]);
        uint32_t hi = f2bf_rne(W[(size_t)(kb + 2 * p + 1) * FOUT + col]);
        d[p] = lo | (hi << 16);
    }
    ((uint4*)(ws + WSFRAG))[q] = make_uint4(d[0], d[1], d[2], d[3]);
}

// 256 blocks (one per CU, one per bt-slab PAIR); wave w: 64 channels,
// per slab 2 m-tiles x 4 n-tiles x 4 k-steps = 32 MFMAs (64 total).
__global__ __launch_bounds__(256) void k_conv(const float* __restrict__ x,
                                              float* ws)
{
    __shared__ uint16_t asB[2][32 * AROW]; // 17.4 KB bf16 A, pre-shifted
    __shared__ float sumL[FOUT], sqL[FOUT];

    const int bp = blockIdx.x;             // slab pair: bt = 2*bp, 2*bp+1
    const int t  = threadIdx.x;

    const int w     = t >> 6;              // wave id -> channel group w*64
    const int l     = t & 63;
    const int row16 = l & 15;
    const int koct  = l >> 4;

    // B fragments FIRST: 16 dwordx4/lane; reused for BOTH slabs.
    const uint4* wsw = (const uint4*)(ws + WSFRAG);
    uint4 bu[4][4];
    #pragma unroll
    for (int nt = 0; nt < 4; nt++)
        #pragma unroll
        for (int ks = 0; ks < 4; ks++)
            bu[nt][ks] = wsw[(((w * 4 + nt) * 4 + ks) << 6) + l];

    // zero pad rows 21..31 of both buffers
    for (int i = t; i < 1408; i += 256) {
        int sl = (i >= 704);
        int j  = i - sl * 704;
        int r  = 21 + (j >> 6);
        int c2 = (j & 63) << 1;
        *(uint32_t*)&asB[sl][r * AROW + c2] = 0u;
    }
    // stage both slabs: pair's x is contiguous (42 rows x 128)
    const float4* xin4 = (const float4*)(x + (size_t)(2 * bp) * (NPOS * CIN));
    for (int i = t; i < 1344; i += 256) {  // 2*672 dwordx4
        float4 v = xin4[i];                // fully coalesced 16B load
        int base = i << 2;                 // element = r*128 + c, r in 0..41
        int r  = base >> 7;
        int sl = (r >= NPOS);
        int rl = r - sl * NPOS;
        int c  = base & (CIN - 1);
        int s  = c % NPOS;                 // c..c+3 share r (c <= 124)
        int n0 = rl + s; if (n0 >= NPOS) n0 -= NPOS;
        int n1 = n0 + 1; if (n1 >= NPOS) n1 -= NPOS;
        int n2 = n1 + 1; if (n2 >= NPOS) n2 -= NPOS;
        int n3 = n2 + 1; if (n3 >= NPOS) n3 -= NPOS;
        uint16_t* ab = asB[sl];
        ab[n0 * AROW + c    ] = f2bf_rne(v.x);
        ab[n1 * AROW + c + 1] = f2bf_rne(v.y);
        ab[n2 * AROW + c + 2] = f2bf_rne(v.z);
        ab[n3 * AROW + c + 3] = f2bf_rne(v.w);
    }

    v8s bfr[4][4];
    #pragma unroll
    for (int nt = 0; nt < 4; nt++)
        #pragma unroll
        for (int ks = 0; ks < 4; ks++)
            bfr[nt][ks] = __builtin_bit_cast(v8s, bu[nt][ks]);
    __syncthreads();

    // ---------- MFMA + epilogue per slab; stats carried across both ----------
    float s4[4] = {0.f, 0.f, 0.f, 0.f};
    float q4[4] = {0.f, 0.f, 0.f, 0.f};
    uint16_t* yws = (uint16_t*)(ws + WSY);

    #pragma unroll
    for (int sl = 0; sl < 2; sl++) {
        v4f acc[2][4];                     // reused between slabs
        #pragma unroll
        for (int m = 0; m < 2; m++)
            #pragma unroll
            for (int nt = 0; nt < 4; nt++) acc[m][nt] = (v4f){0.f, 0.f, 0.f, 0.f};

        #pragma unroll
        for (int m = 0; m < 2; m++) {
            v8s afr[4];
            #pragma unroll
            for (int ks = 0; ks < 4; ks++) // ds_read_b128, 16B-aligned
                afr[ks] = *(const v8s*)&asB[sl][(m * 16 + row16) * AROW + ks * 32 + koct * 8];
            #pragma unroll
            for (int ks = 0; ks < 4; ks++)
                #pragma unroll
                for (int nt = 0; nt < 4; nt++)
                    acc[m][nt] = __builtin_amdgcn_mfma_f32_16x16x32_bf16(
                                     afr[ks], bfr[nt][ks], acc[m][nt], 0, 0, 0);
        }

        uint16_t* yout = yws + (size_t)(2 * bp + sl) * (NPOS * FOUT) + w * 64;
        #pragma unroll
        for (int nt = 0; nt < 4; nt++) {
            #pragma unroll
            for (int m = 0; m < 2; m++)
                #pragma unroll
                for (int rg = 0; rg < 4; rg++) {
                    float v = acc[m][nt][rg];   // pad rows contribute 0
                    s4[nt] += v; q4[nt] += v * v;
                    int gr = m * 16 + koct * 4 + rg;  // C/D: col=row16
                    if (gr < NPOS)
                        yout[(size_t)gr * FOUT + nt * 16 + row16] = f2bf_rne(v);
                }
        }
    }

    #pragma unroll
    for (int nt = 0; nt < 4; nt++) {
        float s = s4[nt], q = q4[nt];
        s += __shfl_xor(s, 16); s += __shfl_xor(s, 32);
        q += __shfl_xor(q, 16); q += __shfl_xor(q, 32);
        if (l < 16) {
            sumL[w * 64 + nt * 16 + l] = s;
            sqL [w * 64 + nt * 16 + l] = q;
        }
    }
    __syncthreads();

    // 32-way spread, 256 blocks -> 8 adds/address
    float* part = ws + (bp & (PARTS - 1)) * 512;
    atomicAdd(part + t, sumL[t]);
    atomicAdd(part + 256 + t, sqL[t]);
}

// 672 blocks: each handles 16 m-rows. sc/bs once per block into LDS
// (coalesced partial reads), then 2 iterations of bf16->f32 normalize.
__global__ __launch_bounds__(256) void k_bnapply(const float* __restrict__ ws,
                                                 const float* __restrict__ gamma,
                                                 const float* __restrict__ beta,
                                                 float* __restrict__ y)
{
    __shared__ float scL[FOUT], bsL[FOUT];
    const int t = threadIdx.x;

    {   // channel t: sum the 32 partials (coalesced: consecutive t)
        float s = 0.f, q = 0.f;
        #pragma unroll
        for (int p = 0; p < PARTS; p++) {
            s += ws[p * 512 + t];
            q += ws[p * 512 + 256 + t];
        }
        const float invM = 1.0f / (float)M_TOTAL;
        float mean = s * invM;
        float var  = fmaf(-mean, mean, q * invM);
        float sc   = rsqrtf(var + BN_EPS) * gamma[t];
        scL[t] = sc;
        bsL[t] = beta[t] - mean * sc;
    }
    __syncthreads();

    const int fb = (t & 31) << 3;          // this thread's 8-channel base
    const uint16_t* yws = (const uint16_t*)(ws + WSY);
    const float4 sc0 = *(const float4*)&scL[fb];
    const float4 sc1 = *(const float4*)&scL[fb + 4];
    const float4 bs0 = *(const float4*)&bsL[fb];
    const float4 bs1 = *(const float4*)&bsL[fb + 4];

    #pragma unroll
    for (int it = 0; it < 2; it++) {
        int m = blockIdx.x * 16 + it * 8 + (t >> 5);
        uint4 u = *(const uint4*)(yws + (size_t)m * FOUT + fb);
        float4 o0, o1;
        o0.x = fmaxf(fmaf(bf2f_lo(u.x), sc0.x, bs0.x), 0.0f);
        o0.y = fmaxf(fmaf(bf2f_hi(u.x), sc0.y, bs0.y), 0.0f);
        o0.z = fmaxf(fmaf(bf2f_lo(u.y), sc0.z, bs0.z), 0.0f);
        o0.w = fmaxf(fmaf(bf2f_hi(u.y), sc0.w, bs0.w), 0.0f);
        o1.x = fmaxf(fmaf(bf2f_lo(u.z), sc1.x, bs1.x), 0.0f);
        o1.y = fmaxf(fmaf(bf2f_hi(u.z), sc1.y, bs1.y), 0.0f);
        o1.z = fmaxf(fmaf(bf2f_lo(u.w), sc1.z, bs1.z), 0.0f);
        o1.w = fmaxf(fmaf(bf2f_hi(u.w), sc1.w, bs1.w), 0.0f);
        float* yo = y + (size_t)m * FOUT + fb;
        *(float4*)yo       = o0;
        *(float4*)(yo + 4) = o1;
    }
}

// Template-named symbol kept defined (harness-compat; not launched).
extern "C" __global__ void SpatialShiftConvBlock_71923522339050_kernel() {}

extern "C" void kernel_launch(void* const* d_in, const int* in_sizes, int n_in,
                              void* d_out, int out_size, void* d_ws, size_t ws_size,
                              hipStream_t stream) {
    float* y  = (float*)d_out;             // FLOAT32 output
    float* ws = (float*)d_ws;              // 32x partials | W frags | bf16 y
    k_prep<<<16, 256, 0, stream>>>((const float*)d_in[1], ws);
    k_conv<<<BT / 2, 256, 0, stream>>>((const float*)d_in[0], ws);
    k_bnapply<<<672, 256, 0, stream>>>(ws, (const float*)d_in[3],
                                       (const float*)d_in[4], y);
}

// Round 19
// 77.946 us; speedup vs baseline: 1.0064x; 1.0064x over previous
//
#include <hip/hip_runtime.h>
#include <stdint.h>

// SpatialShiftConvBlock (B=8,T=64,N=21,C=128,F=256):
//   xs[b,t,n,c] = x[b,t,(n - c%21) mod 21, c]       (per-channel circular roll)
//   y  = xs @ W (+ b == 0, and bias cancels in BN anyway)
//   y  = (y - mean)*rsqrt(var + 1e-3)*gamma + beta  (BN training stats over B,T,N)
//   out = relu(y)  (float32 output)
//
// R47 = R45 (77.3us, best; R46 slab-pairing was neutral -> reverted) +
// coalesced y-store epilogue:
//  The MFMA C/D layout made each bf16 y store a 4-segment wave instruction
//  (4 rows x 32B), 42/thread ~= 168 VMEM issues/wave/slab. Now: acc ->
//  ybuf[21][272] in LDS (row stride 544B = 136 dw == 8 mod 32 -> the 4 koct
//  groups hit disjoint bank octets, 2 lanes/bank = free), barrier (merged
//  with stats barrier), then 672 fully-coalesced dwordx4 stores per block.
//  Everything else identical to R45: hoisted B-frags, float4 staging,
//  PARTS=32 spread, k_prep 16-blk, k_bnapply 672-blk.
// Frag maps (HW-verified m89): A: row=l&15,k=(l>>4)*8+j; B: col=l&15 same k;
// C/D: col=l&15,row=(l>>4)*4+reg.
// ws floats: [0:16384] 32x{256 sums,256 sumsqs}; [16384:32768] bf16 W frags;
// [32768:...] bf16 pre-norm y [10752][256] (5.5MB).
// fillBufferAligned (~41us harness ws re-poison) is an unconditional tax.

#define NPOS 21
#define CIN  128
#define FOUT 256
#define BT   512            // B*T
#define M_TOTAL 10752       // BT*NPOS
#define BN_EPS 1e-3f
#define AROW 136            // A LDS row stride in bf16 (272B: 16B-aligned)
#define YROW 272            // ybuf row stride in bf16 (544B: 16B-aligned,
                            //  136 dw == 8 mod 32 -> koct groups bank-disjoint)
#define PARTS 32
#define WSFRAG 16384        // float offset of W frags
#define WSY    32768        // float offset of bf16 pre-norm y

typedef short v8s __attribute__((ext_vector_type(8)));   // 8 bf16 (4 VGPR)
typedef float v4f __attribute__((ext_vector_type(4)));   // 4 f32 acc

__device__ __forceinline__ uint16_t f2bf_rne(float f) {
    uint32_t u = __builtin_bit_cast(uint32_t, f);
    u += 0x7FFFu + ((u >> 16) & 1u);                     // round-nearest-even
    return (uint16_t)(u >> 16);
}
__device__ __forceinline__ float bf2f_lo(uint32_t d) {
    return __builtin_bit_cast(float, d << 16);
}
__device__ __forceinline__ float bf2f_hi(uint32_t d) {
    return __builtin_bit_cast(float, d & 0xFFFF0000u);
}

// 16 blocks x 256: zero the 32 partial arrays (64KB); convert W -> bf16 frags.
__global__ __launch_bounds__(256) void k_prep(const float* __restrict__ W,
                                              float* __restrict__ ws)
{
    const int t = threadIdx.x;
    const int b = blockIdx.x;
    ((float4*)ws)[b * 256 + t] = make_float4(0.f, 0.f, 0.f, 0.f);  // [0:16384]

    const int q  = b * 256 + t;                          // frag id 0..4095
    const int l  = q & 63;
    const int ks = (q >> 6) & 3;
    const int nt = q >> 8;                               // n-tile 0..15
    const int kb = ks * 32 + (l >> 4) * 8;
    const int col = nt * 16 + (l & 15);
    uint32_t d[4];
    #pragma unroll
    for (int p = 0; p < 4; p++) {
        uint32_t lo = f2bf_rne(W[(size_t)(kb + 2 * p    ) * FOUT + col]);
        uint32_t hi = f2bf_rne(W[(size_t)(kb + 2 * p + 1) * FOUT + col]);
        d[p] = lo | (hi << 16);
    }
    ((uint4*)(ws + WSFRAG))[q] = make_uint4(d[0], d[1], d[2], d[3]);
}

// 512 blocks (one per bt-slab), full F per block; wave w: 64 channels,
// 2 m-tiles x 4 n-tiles x 4 k-steps = 32 MFMAs. Pre-norm y stored bf16 in ws.
__global__ __launch_bounds__(256) void k_conv(const float* __restrict__ x,
                                              float* ws)
{
    __shared__ uint16_t asB[32 * AROW];    // 8.7 KB bf16 A, pre-shifted
    __shared__ uint16_t ybuf[NPOS * YROW]; // 11.4 KB bf16 y staging
    __shared__ float sumL[FOUT], sqL[FOUT];

    const int bt = blockIdx.x;
    const int t  = threadIdx.x;

    const int w     = t >> 6;              // wave id -> channel group w*64
    const int l     = t & 63;
    const int row16 = l & 15;
    const int koct  = l >> 4;

    // B fragments FIRST: 16 dwordx4/lane; L2 latency overlaps staging below.
    const uint4* wsw = (const uint4*)(ws + WSFRAG);
    uint4 bu[4][4];
    #pragma unroll
    for (int nt = 0; nt < 4; nt++)
        #pragma unroll
        for (int ks = 0; ks < 4; ks++)
            bu[nt][ks] = wsw[(((w * 4 + nt) * 4 + ks) << 6) + l];

    // ---------- stage shifted bf16 A-slab (float4 loads) ----------
    for (int i = t; i < 704; i += 256) {   // zero pad rows 21..31
        int r  = 21 + (i >> 6);
        int c2 = (i & 63) << 1;
        *(uint32_t*)&asB[r * AROW + c2] = 0u;
    }
    const float4* xin4 = (const float4*)(x + (size_t)bt * (NPOS * CIN));
    for (int i = t; i < (NPOS * CIN) / 4; i += 256) {    // 672 dwordx4/block
        float4 v = xin4[i];                // fully coalesced 16B load
        int base = i << 2;                 // element index = r*128 + c
        int r = base >> 7;
        int c = base & (CIN - 1);
        int s = c % NPOS;                  // shift for c (c..c+3 same r: c<=124)
        int n0 = r + s; if (n0 >= NPOS) n0 -= NPOS;
        int n1 = n0 + 1; if (n1 >= NPOS) n1 -= NPOS;
        int n2 = n1 + 1; if (n2 >= NPOS) n2 -= NPOS;
        int n3 = n2 + 1; if (n3 >= NPOS) n3 -= NPOS;
        asB[n0 * AROW + c    ] = f2bf_rne(v.x);
        asB[n1 * AROW + c + 1] = f2bf_rne(v.y);
        asB[n2 * AROW + c + 2] = f2bf_rne(v.z);
        asB[n3 * AROW + c + 3] = f2bf_rne(v.w);
    }

    v8s bfr[4][4];
    #pragma unroll
    for (int nt = 0; nt < 4; nt++)
        #pragma unroll
        for (int ks = 0; ks < 4; ks++)
            bfr[nt][ks] = __builtin_bit_cast(v8s, bu[nt][ks]);
    __syncthreads();

    // ---------- MFMA ----------
    v4f acc[2][4];
    #pragma unroll
    for (int m = 0; m < 2; m++)
        #pragma unroll
        for (int nt = 0; nt < 4; nt++) acc[m][nt] = (v4f){0.f, 0.f, 0.f, 0.f};

    #pragma unroll
    for (int m = 0; m < 2; m++) {
        v8s afr[4];
        #pragma unroll
        for (int ks = 0; ks < 4; ks++)     // ds_read_b128, 16B-aligned
            afr[ks] = *(const v8s*)&asB[(m * 16 + row16) * AROW + ks * 32 + koct * 8];
        #pragma unroll
        for (int ks = 0; ks < 4; ks++)
            #pragma unroll
            for (int nt = 0; nt < 4; nt++)
                acc[m][nt] = __builtin_amdgcn_mfma_f32_16x16x32_bf16(
                                 afr[ks], bfr[nt][ks], acc[m][nt], 0, 0, 0);
    }

    // ---------- epilogue: acc -> ybuf (LDS, bank-spread) + channel sums ----
    #pragma unroll
    for (int nt = 0; nt < 4; nt++) {
        float s = 0.f, q = 0.f;
        #pragma unroll
        for (int m = 0; m < 2; m++)
            #pragma unroll
            for (int rg = 0; rg < 4; rg++) {
                float v = acc[m][nt][rg];  // pad rows contribute exactly 0
                s += v; q += v * v;
                int gr = m * 16 + koct * 4 + rg;   // C/D: col=row16, row=koct*4+rg
                if (gr < NPOS)
                    ybuf[gr * YROW + w * 64 + nt * 16 + row16] = f2bf_rne(v);
            }
        s += __shfl_xor(s, 16); s += __shfl_xor(s, 32);
        q += __shfl_xor(q, 16); q += __shfl_xor(q, 32);
        if (l < 16) {
            sumL[w * 64 + nt * 16 + l] = s;
            sqL [w * 64 + nt * 16 + l] = q;
        }
    }
    __syncthreads();                       // ybuf + sums ready

    // coalesced y flush: 672 dwordx4/block (was 42 4-segment stores/thread)
    uint16_t* yws = (uint16_t*)(ws + WSY);
    uint4* ydst = (uint4*)(yws + (size_t)bt * (NPOS * FOUT));
    for (int i = t; i < 672; i += 256) {
        int row = i >> 5;                  // 32 uint4 per 256-ch row
        int c   = i & 31;
        ydst[i] = *(const uint4*)&ybuf[row * YROW + (c << 3)];
    }

    // 32-way spread: 16 adds/address
    float* part = ws + (bt & (PARTS - 1)) * 512;
    atomicAdd(part + t, sumL[t]);
    atomicAdd(part + 256 + t, sqL[t]);
}

// 672 blocks: each handles 16 m-rows. sc/bs once per block into LDS
// (coalesced partial reads), then 2 iterations of bf16->f32 normalize.
__global__ __launch_bounds__(256) void k_bnapply(const float* __restrict__ ws,
                                                 const float* __restrict__ gamma,
                                                 const float* __restrict__ beta,
                                                 float* __restrict__ y)
{
    __shared__ float scL[FOUT], bsL[FOUT];
    const int t = threadIdx.x;

    {   // channel t: sum the 32 partials (coalesced: consecutive t)
        float s = 0.f, q = 0.f;
        #pragma unroll
        for (int p = 0; p < PARTS; p++) {
            s += ws[p * 512 + t];
            q += ws[p * 512 + 256 + t];
        }
        const float invM = 1.0f / (float)M_TOTAL;
        float mean = s * invM;
        float var  = fmaf(-mean, mean, q * invM);
        float sc   = rsqrtf(var + BN_EPS) * gamma[t];
        scL[t] = sc;
        bsL[t] = beta[t] - mean * sc;
    }
    __syncthreads();

    const int fb = (t & 31) << 3;          // this thread's 8-channel base
    const uint16_t* yws = (const uint16_t*)(ws + WSY);
    const float4 sc0 = *(const float4*)&scL[fb];
    const float4 sc1 = *(const float4*)&scL[fb + 4];
    const float4 bs0 = *(const float4*)&bsL[fb];
    const float4 bs1 = *(const float4*)&bsL[fb + 4];

    #pragma unroll
    for (int it = 0; it < 2; it++) {
        int m = blockIdx.x * 16 + it * 8 + (t >> 5);
        uint4 u = *(const uint4*)(yws + (size_t)m * FOUT + fb);
        float4 o0, o1;
        o0.x = fmaxf(fmaf(bf2f_lo(u.x), sc0.x, bs0.x), 0.0f);
        o0.y = fmaxf(fmaf(bf2f_hi(u.x), sc0.y, bs0.y), 0.0f);
        o0.z = fmaxf(fmaf(bf2f_lo(u.y), sc0.z, bs0.z), 0.0f);
        o0.w = fmaxf(fmaf(bf2f_hi(u.y), sc0.w, bs0.w), 0.0f);
        o1.x = fmaxf(fmaf(bf2f_lo(u.z), sc1.x, bs1.x), 0.0f);
        o1.y = fmaxf(fmaf(bf2f_hi(u.z), sc1.y, bs1.y), 0.0f);
        o1.z = fmaxf(fmaf(bf2f_lo(u.w), sc1.z, bs1.z), 0.0f);
        o1.w = fmaxf(fmaf(bf2f_hi(u.w), sc1.w, bs1.w), 0.0f);
        float* yo = y + (size_t)m * FOUT + fb;
        *(float4*)yo       = o0;
        *(float4*)(yo + 4) = o1;
    }
}

// Template-named symbol kept defined (harness-compat; not launched).
extern "C" __global__ void SpatialShiftConvBlock_71923522339050_kernel() {}

extern "C" void kernel_launch(void* const* d_in, const int* in_sizes, int n_in,
                              void* d_out, int out_size, void* d_ws, size_t ws_size,
                              hipStream_t stream) {
    float* y  = (float*)d_out;             // FLOAT32 output
    float* ws = (float*)d_ws;              // 32x partials | W frags | bf16 y
    k_prep<<<16, 256, 0, stream>>>((const float*)d_in[1], ws);
    k_conv<<<BT, 256, 0, stream>>>((const float*)d_in[0], ws);
    k_bnapply<<<672, 256, 0, stream>>>(ws, (const float*)d_in[3],
                                       (const float*)d_in[4], y);
}